// Round 3
// baseline (953.315 us; speedup 1.0000x reference)
//
#include <hip/hip_runtime.h>
#include <hip/hip_bf16.h>

#define NPTS 1024
#define KNN_K 20

// ---------------------------------------------------------------------------
// kNN: one block = 8 query rows of one batch, 512 threads (8 waves).
// Phase 1: distance matrix into LDS (each thread: 8 rows x 2 cols).
// Phase 2: per-row top-20, one 64-lane wave per row, values in registers.
// Distance accumulation order over c matches the previously-validated kernel
// exactly (same fmaf chains), so selected indices are identical.
template<int C>
__global__ __launch_bounds__(512, 6)
void knn_kernel(const float* __restrict__ x, int* __restrict__ knn_idx,
                int in_bstride)
{
    __shared__ float dist[8][NPTS];      // 32 KB
    __shared__ float xn[8][C];
    __shared__ float xxr[8];
    const int b  = blockIdx.x >> 7;            // 128 row-groups per batch
    const int n0 = (blockIdx.x & 127) << 3;
    const int tid = threadIdx.x;               // 0..511
    const float* xb = x + (size_t)b * in_bstride;

    for (int i = tid; i < 8 * C; i += 512) {
        const int r = i / C, c = i - r * C;
        xn[r][c] = xb[c * NPTS + n0 + r];
    }
    __syncthreads();
    if (tid < 8) {
        float s = 0.f;
        for (int c = 0; c < C; c++) s = fmaf(xn[tid][c], xn[tid][c], s);
        xxr[tid] = s;
    }
    __syncthreads();

    // --- distance phase: each thread owns m = 2*tid, 2*tid+1 ---
    float acc[8][2];
    #pragma unroll
    for (int r = 0; r < 8; r++) acc[r][0] = acc[r][1] = 0.f;
    float sq[2] = {0.f, 0.f};                  // xx[m] on the fly
    const int m0 = tid * 2;

    if constexpr (C % 4 == 0) {
        for (int c4 = 0; c4 < C; c4 += 4) {
            float4 xnv[8];
            #pragma unroll
            for (int r = 0; r < 8; r++)
                xnv[r] = *reinterpret_cast<const float4*>(&xn[r][c4]);
            #pragma unroll
            for (int u = 0; u < 4; u++) {
                const float2 xm = *reinterpret_cast<const float2*>(xb + (c4 + u) * NPTS + m0);
                sq[0] = fmaf(xm.x, xm.x, sq[0]);
                sq[1] = fmaf(xm.y, xm.y, sq[1]);
                #pragma unroll
                for (int r = 0; r < 8; r++) {
                    const float xv = (u == 0) ? xnv[r].x : (u == 1) ? xnv[r].y
                                   : (u == 2) ? xnv[r].z : xnv[r].w;
                    acc[r][0] = fmaf(xv, xm.x, acc[r][0]);
                    acc[r][1] = fmaf(xv, xm.y, acc[r][1]);
                }
            }
        }
    } else {
        for (int c = 0; c < C; c++) {
            const float2 xm = *reinterpret_cast<const float2*>(xb + c * NPTS + m0);
            sq[0] = fmaf(xm.x, xm.x, sq[0]);
            sq[1] = fmaf(xm.y, xm.y, sq[1]);
            #pragma unroll
            for (int r = 0; r < 8; r++) {
                const float xv = xn[r][c];
                acc[r][0] = fmaf(xv, xm.x, acc[r][0]);
                acc[r][1] = fmaf(xv, xm.y, acc[r][1]);
            }
        }
    }
    #pragma unroll
    for (int r = 0; r < 8; r++) {
        float2 dv;
        dv.x = 2.f * acc[r][0] - xxr[r] - sq[0];
        dv.y = 2.f * acc[r][1] - xxr[r] - sq[1];
        *reinterpret_cast<float2*>(&dist[r][m0]) = dv;
    }
    __syncthreads();

    // --- top-k phase: one 64-lane wave per row, 16 values per lane ---
    const int r    = tid >> 6;
    const int lane = tid & 63;
    float v[16];
    #pragma unroll
    for (int q = 0; q < 16; q++) v[q] = dist[r][lane + 64 * q];

    float lv = v[0]; int lq = 0;
    #pragma unroll
    for (int q = 1; q < 16; q++) if (v[q] > lv) { lv = v[q]; lq = q; }

    int* outp = knn_idx + ((size_t)(b * NPTS + n0 + r)) * KNN_K;
    for (int k = 0; k < KNN_K; k++) {
        float bv_ = lv;
        int   bm  = lane + 64 * lq;
        #pragma unroll
        for (int off = 32; off; off >>= 1) {
            const float ov = __shfl_xor(bv_, off);
            const int   om = __shfl_xor(bm, off);
            if (ov > bv_ || (ov == bv_ && om < bm)) { bv_ = ov; bm = om; }
        }
        if (lane == 0) outp[k] = bm;
        const int wl = bm & 63, wq = bm >> 6;
        if (lane == wl) {
            #pragma unroll
            for (int q = 0; q < 16; q++) if (q == wq) v[q] = -INFINITY;
            lv = v[0]; lq = 0;
            #pragma unroll
            for (int q = 1; q < 16; q++) if (v[q] > lv) { lv = v[q]; lq = q; }
        }
    }
}

// ---------------------------------------------------------------------------
// Per-batch GEMM (64x64 tile, 4x4/thread):
//   Z[b,o,n] = sum_c w[o,c]*x[b,c,n]   (+ Z2 with w[o,C+c] when DUAL)
template<bool DUAL>
__global__ __launch_bounds__(256)
void mm_kernel(const float* __restrict__ xin, const float* __restrict__ w,
               float* __restrict__ Z, float* __restrict__ Z2,
               int C, int O, int in_bstride, int wstride)
{
    __shared__ float xs[32][64];
    __shared__ float ws1[32][68];
    __shared__ float ws2[32][68];
    const int n0 = blockIdx.x * 64;
    const int o0 = blockIdx.y * 64;
    const int b  = blockIdx.z;
    const int tid = threadIdx.x;
    const int nl = (tid & 15) * 4;
    const int ol = (tid >> 4) * 4;
    float a1[4][4] = {{0.f}};
    float a2[4][4] = {{0.f}};
    const float* xb = xin + (size_t)b * in_bstride;

    for (int cc = 0; cc < C; cc += 32) {
        #pragma unroll
        for (int t = 0; t < 8; t++) {
            const int id = tid + t * 256;
            const int j = id >> 6, nn = id & 63;
            const int c = cc + j;
            xs[j][nn] = (c < C) ? xb[c * NPTS + n0 + nn] : 0.f;
        }
        #pragma unroll
        for (int t = 0; t < 8; t++) {
            const int id = tid + t * 256;
            const int j = id & 31, i = id >> 5;
            const int c = cc + j;
            ws1[j][i] = (c < C) ? w[(o0 + i) * wstride + c] : 0.f;
            if (DUAL) ws2[j][i] = (c < C) ? w[(o0 + i) * wstride + C + c] : 0.f;
        }
        __syncthreads();
        #pragma unroll
        for (int j = 0; j < 32; j++) {
            const float4 xv = *reinterpret_cast<const float4*>(&xs[j][nl]);
            const float4 wv = *reinterpret_cast<const float4*>(&ws1[j][ol]);
            const float xr[4] = {xv.x, xv.y, xv.z, xv.w};
            const float wr[4] = {wv.x, wv.y, wv.z, wv.w};
            #pragma unroll
            for (int oi = 0; oi < 4; oi++)
                #pragma unroll
                for (int ni = 0; ni < 4; ni++)
                    a1[oi][ni] = fmaf(wr[oi], xr[ni], a1[oi][ni]);
            if (DUAL) {
                const float4 w2 = *reinterpret_cast<const float4*>(&ws2[j][ol]);
                const float w2r[4] = {w2.x, w2.y, w2.z, w2.w};
                #pragma unroll
                for (int oi = 0; oi < 4; oi++)
                    #pragma unroll
                    for (int ni = 0; ni < 4; ni++)
                        a2[oi][ni] = fmaf(w2r[oi], xr[ni], a2[oi][ni]);
            }
        }
        __syncthreads();
    }

    #pragma unroll
    for (int oi = 0; oi < 4; oi++) {
        const int o = o0 + ol + oi;
        const float4 r1 = make_float4(a1[oi][0], a1[oi][1], a1[oi][2], a1[oi][3]);
        *reinterpret_cast<float4*>(Z + ((size_t)b * O + o) * NPTS + n0 + nl) = r1;
        if (DUAL) {
            const float4 r2 = make_float4(a2[oi][0], a2[oi][1], a2[oi][2], a2[oi][3]);
            *reinterpret_cast<float4*>(Z2 + ((size_t)b * O + o) * NPTS + n0 + nl) = r2;
        }
    }
}

// ---------------------------------------------------------------------------
// Layer-5 GEMM: C=O=512 fixed. 128n x 64o tile, 8x4/thread, fused affine+leaky.
// out[b,o,n] = leaky(s[o]*sum_c w[o,c]*x[b,c,n] + bias[o])
__global__ __launch_bounds__(256, 4)
void mm5_kernel(const float* __restrict__ xin, const float* __restrict__ w,
                const float* __restrict__ sv, const float* __restrict__ bvec,
                float* __restrict__ out)
{
    __shared__ float xs[32][128];    // 16 KB
    __shared__ float ws[32][68];     // 8.7 KB
    const int n0 = blockIdx.x * 128;
    const int o0 = blockIdx.y * 64;
    const int b  = blockIdx.z;
    const int tid = threadIdx.x;
    const int nl = (tid & 15) * 8;
    const int ol = (tid >> 4) * 4;
    float acc[4][8] = {{0.f}};
    const float* xb = xin + (size_t)b * (512 * NPTS);

    for (int cc = 0; cc < 512; cc += 32) {
        #pragma unroll
        for (int t = 0; t < 4; t++) {          // xs: 1024 float4s, 4/thread
            const int f = tid + t * 256;
            const int j = f >> 5, col = (f & 31) * 4;
            *reinterpret_cast<float4*>(&xs[j][col]) =
                *reinterpret_cast<const float4*>(&xb[(cc + j) * NPTS + n0 + col]);
        }
        #pragma unroll
        for (int t = 0; t < 2; t++) {          // ws: 64 o-rows x 32 c, transpose
            const int id = tid + t * 256;
            const int i = id & 63, jq = (id >> 6) * 4;
            const float4 wv = *reinterpret_cast<const float4*>(&w[(o0 + i) * 512 + cc + jq]);
            ws[jq + 0][i] = wv.x;
            ws[jq + 1][i] = wv.y;
            ws[jq + 2][i] = wv.z;
            ws[jq + 3][i] = wv.w;
        }
        __syncthreads();
        #pragma unroll
        for (int j = 0; j < 32; j++) {
            float xr[8], wr[4];
            *reinterpret_cast<float4*>(&xr[0]) = *reinterpret_cast<const float4*>(&xs[j][nl]);
            *reinterpret_cast<float4*>(&xr[4]) = *reinterpret_cast<const float4*>(&xs[j][nl + 4]);
            *reinterpret_cast<float4*>(&wr[0]) = *reinterpret_cast<const float4*>(&ws[j][ol]);
            #pragma unroll
            for (int oi = 0; oi < 4; oi++)
                #pragma unroll
                for (int ni = 0; ni < 8; ni++)
                    acc[oi][ni] = fmaf(wr[oi], xr[ni], acc[oi][ni]);
        }
        __syncthreads();
    }

    #pragma unroll
    for (int oi = 0; oi < 4; oi++) {
        const int o = o0 + ol + oi;
        const float s = sv[o], bb = bvec[o];
        float* zp = out + ((size_t)b * 512 + o) * NPTS + n0 + nl;
        #pragma unroll
        for (int h = 0; h < 2; h++) {
            float4 r;
            r.x = fmaf(s, acc[oi][h * 4 + 0], bb);
            r.y = fmaf(s, acc[oi][h * 4 + 1], bb);
            r.z = fmaf(s, acc[oi][h * 4 + 2], bb);
            r.w = fmaf(s, acc[oi][h * 4 + 3], bb);
            r.x = r.x >= 0.f ? r.x : 0.2f * r.x;
            r.y = r.y >= 0.f ? r.y : 0.2f * r.y;
            r.z = r.z >= 0.f ? r.z : 0.2f * r.z;
            r.w = r.w >= 0.f ? r.w : 0.2f * r.w;
            *reinterpret_cast<float4*>(zp + h * 4) = r;
        }
    }
}

// ---------------------------------------------------------------------------
// out[b, cho+o, n] = leaky(s[o]*(max_k Z[b,o,idx[b,n,k]] - Z[b,o,n] + Z2[b,o,n]) + bias[o])
__global__ __launch_bounds__(256)
void gather_kernel(const float* __restrict__ Z, const float* __restrict__ Z2,
                   const int* __restrict__ knn_idx,
                   const float* __restrict__ sv, const float* __restrict__ bvec,
                   float* __restrict__ outc, int O, int ch_off)
{
    __shared__ int idx_s[64][21];
    const int n0  = blockIdx.x * 64;
    const int og0 = blockIdx.y * 16;
    const int b   = blockIdx.z;
    const int tid = threadIdx.x;
    const int* ig = knn_idx + (size_t)(b * NPTS + n0) * KNN_K;
    for (int i = tid; i < 64 * KNN_K; i += 256) {
        const int nn = i / KNN_K, k = i - nn * KNN_K;
        idx_s[nn][k] = ig[i];
    }
    __syncthreads();
    const int nn = tid & 63;
    const int oo = tid >> 6;
    const int n  = n0 + nn;
    for (int oc = 0; oc < 16; oc += 4) {
        const int o = og0 + oc + oo;
        const float* zr = Z + ((size_t)b * O + o) * NPTS;
        float mx = -INFINITY;
        #pragma unroll
        for (int k = 0; k < KNN_K; k++)
            mx = fmaxf(mx, zr[idx_s[nn][k]]);
        const float cz = zr[n];
        const float z2 = Z2[((size_t)b * O + o) * NPTS + n];
        float y = fmaf(sv[o], (mx - cz + z2), bvec[o]);
        y = y >= 0.f ? y : 0.2f * y;
        outc[(size_t)b * (512 * NPTS) + (size_t)(ch_off + o) * NPTS + n] = y;
    }
}

// ---------------------------------------------------------------------------
// p_max/p_avg over n; x_equ[b, 0:512]=max, [512:1024]=mean
__global__ __launch_bounds__(256)
void reduce_kernel(const float* __restrict__ xinv, float* __restrict__ xequ)
{
    const int b = blockIdx.x >> 9;
    const int o = blockIdx.x & 511;
    const float* row = xinv + (size_t)blockIdx.x * NPTS;
    const int tid = threadIdx.x;
    const float4 val = *reinterpret_cast<const float4*>(&row[tid * 4]);
    float mx = fmaxf(fmaxf(val.x, val.y), fmaxf(val.z, val.w));
    float sm = (val.x + val.y) + (val.z + val.w);
    #pragma unroll
    for (int off = 32; off; off >>= 1) {
        mx = fmaxf(mx, __shfl_down(mx, off));
        sm += __shfl_down(sm, off);
    }
    __shared__ float smx[4], ssm[4];
    if ((tid & 63) == 0) { smx[tid >> 6] = mx; ssm[tid >> 6] = sm; }
    __syncthreads();
    if (tid == 0) {
        mx = fmaxf(fmaxf(smx[0], smx[1]), fmaxf(smx[2], smx[3]));
        sm = (ssm[0] + ssm[1]) + (ssm[2] + ssm[3]);
        xequ[b * 1024 + o] = mx;
        xequ[b * 1024 + 512 + o] = sm * (1.0f / 1024.0f);
    }
}

// ---------------------------------------------------------------------------
extern "C" void kernel_launch(void* const* d_in, const int* in_sizes, int n_in,
                              void* d_out, int out_size, void* d_ws, size_t ws_size,
                              hipStream_t stream)
{
    const float* x  = (const float*)d_in[0];
    const float* w1 = (const float*)d_in[1],  *s1 = (const float*)d_in[2],  *b1 = (const float*)d_in[3];
    const float* w2 = (const float*)d_in[4],  *s2 = (const float*)d_in[5],  *b2 = (const float*)d_in[6];
    const float* w3 = (const float*)d_in[7],  *s3 = (const float*)d_in[8],  *b3 = (const float*)d_in[9];
    const float* w4 = (const float*)d_in[10], *s4 = (const float*)d_in[11], *b4 = (const float*)d_in[12];
    const float* w5 = (const float*)d_in[13], *s5 = (const float*)d_in[14], *b5 = (const float*)d_in[15];

    float* out  = (float*)d_out;
    float* xequ = out;
    float* xinv = out + 16 * 1024;

    float* xc  = (float*)d_ws;                                // (16, 512, 1024)
    float* Z   = xc  + (size_t)16 * 512 * NPTS;               // (16, 256, 1024)
    float* Z2  = Z   + (size_t)16 * 256 * NPTS;               // (16, 256, 1024)
    int*   idxb = (int*)(Z2 + (size_t)16 * 256 * NPTS);       // (16, 1024, 20)

    const int BS_XC = 512 * NPTS;

    // ---- Layer 1: C=3, O=64, in=x ----
    knn_kernel<3><<<2048, 512, 0, stream>>>(x, idxb, 3 * NPTS);
    mm_kernel<true><<<dim3(16, 1, 16), 256, 0, stream>>>(
        x, w1, Z, Z2, 3, 64, 3 * NPTS, 6);
    gather_kernel<<<dim3(16, 4, 16), 256, 0, stream>>>(Z, Z2, idxb, s1, b1, xc, 64, 0);

    // ---- Layer 2: C=64, O=64, in=xc[:,0:64,:] ----
    knn_kernel<64><<<2048, 512, 0, stream>>>(xc, idxb, BS_XC);
    mm_kernel<true><<<dim3(16, 1, 16), 256, 0, stream>>>(
        xc, w2, Z, Z2, 64, 64, BS_XC, 128);
    gather_kernel<<<dim3(16, 4, 16), 256, 0, stream>>>(Z, Z2, idxb, s2, b2, xc, 64, 64);

    // ---- Layer 3: C=64, O=128, in=xc[:,64:128,:] ----
    {
        const float* in3 = xc + (size_t)64 * NPTS;
        knn_kernel<64><<<2048, 512, 0, stream>>>(in3, idxb, BS_XC);
        mm_kernel<true><<<dim3(16, 2, 16), 256, 0, stream>>>(
            in3, w3, Z, Z2, 64, 128, BS_XC, 128);
        gather_kernel<<<dim3(16, 8, 16), 256, 0, stream>>>(Z, Z2, idxb, s3, b3, xc, 128, 128);
    }

    // ---- Layer 4: C=128, O=256, in=xc[:,128:256,:] ----
    {
        const float* in4 = xc + (size_t)128 * NPTS;
        knn_kernel<128><<<2048, 512, 0, stream>>>(in4, idxb, BS_XC);
        mm_kernel<true><<<dim3(16, 4, 16), 256, 0, stream>>>(
            in4, w4, Z, Z2, 128, 256, BS_XC, 256);
        gather_kernel<<<dim3(16, 16, 16), 256, 0, stream>>>(Z, Z2, idxb, s4, b4, xc, 256, 256);
    }

    // ---- Layer 5: 512x512 pointwise conv + affine + leaky -> x_inv ----
    mm5_kernel<<<dim3(8, 8, 16), 256, 0, stream>>>(xc, w5, s5, b5, xinv);

    // ---- global max/mean pool -> x_equ ----
    reduce_kernel<<<8192, 256, 0, stream>>>(xinv, xequ);
}

// Round 6
// 888.455 us; speedup vs baseline: 1.0730x; 1.0730x over previous
//
#include <hip/hip_runtime.h>
#include <hip/hip_bf16.h>

#define NPTS 1024
#define KNN_K 20

// ---------------------------------------------------------------------------
// kNN: one block = 8 query rows of one batch, 512 threads (8 waves).
// Phase 1: distance matrix into LDS; each thread owns 2 columns for all 8
// rows (acc[8][2]); xn row values read as LDS scalar broadcasts (no preload
// -> low VGPR pressure, no spills; round-2-proven pattern).
// Phase 2: per-row top-20, one 64-lane wave per row, 16 values/lane in regs.
// fmaf chain order over c matches the validated round-2 kernel exactly.
template<int C>
__global__ __launch_bounds__(512)
void knn_kernel(const float* __restrict__ x, int* __restrict__ knn_idx,
                int in_bstride)
{
    __shared__ float dist[8][NPTS];      // 32 KB
    __shared__ float xn[8][C];
    __shared__ float xxr[8];
    const int b  = blockIdx.x >> 7;            // 128 row-groups per batch
    const int n0 = (blockIdx.x & 127) << 3;
    const int tid = threadIdx.x;               // 0..511
    const float* xb = x + (size_t)b * in_bstride;

    for (int i = tid; i < 8 * C; i += 512) {
        const int r = i / C, c = i - r * C;
        xn[r][c] = xb[c * NPTS + n0 + r];
    }
    __syncthreads();
    if (tid < 8) {
        float s = 0.f;
        for (int c = 0; c < C; c++) s = fmaf(xn[tid][c], xn[tid][c], s);
        xxr[tid] = s;
    }
    __syncthreads();

    // --- distance phase: each thread owns m = 2*tid, 2*tid+1 ---
    float acc[8][2];
    #pragma unroll
    for (int r = 0; r < 8; r++) acc[r][0] = acc[r][1] = 0.f;
    float sq[2] = {0.f, 0.f};                  // xx[m] on the fly
    const int m0 = tid * 2;
    #pragma unroll 4
    for (int c = 0; c < C; c++) {
        const float2 xm = *reinterpret_cast<const float2*>(xb + c * NPTS + m0);
        sq[0] = fmaf(xm.x, xm.x, sq[0]);
        sq[1] = fmaf(xm.y, xm.y, sq[1]);
        #pragma unroll
        for (int r = 0; r < 8; r++) {
            const float xv = xn[r][c];
            acc[r][0] = fmaf(xv, xm.x, acc[r][0]);
            acc[r][1] = fmaf(xv, xm.y, acc[r][1]);
        }
    }
    #pragma unroll
    for (int r = 0; r < 8; r++) {
        float2 dv;
        dv.x = 2.f * acc[r][0] - xxr[r] - sq[0];
        dv.y = 2.f * acc[r][1] - xxr[r] - sq[1];
        *reinterpret_cast<float2*>(&dist[r][m0]) = dv;
    }
    __syncthreads();

    // --- top-k phase: one 64-lane wave per row, 16 values per lane ---
    const int r    = tid >> 6;
    const int lane = tid & 63;
    float v[16];
    #pragma unroll
    for (int q = 0; q < 16; q++) v[q] = dist[r][lane + 64 * q];

    float lv = v[0]; int lq = 0;
    #pragma unroll
    for (int q = 1; q < 16; q++) if (v[q] > lv) { lv = v[q]; lq = q; }

    int* outp = knn_idx + ((size_t)(b * NPTS + n0 + r)) * KNN_K;
    for (int k = 0; k < KNN_K; k++) {
        float bv_ = lv;
        int   bm  = lane + 64 * lq;
        #pragma unroll
        for (int off = 32; off; off >>= 1) {
            const float ov = __shfl_xor(bv_, off);
            const int   om = __shfl_xor(bm, off);
            if (ov > bv_ || (ov == bv_ && om < bm)) { bv_ = ov; bm = om; }
        }
        if (lane == 0) outp[k] = bm;
        const int wl = bm & 63, wq = bm >> 6;
        if (lane == wl) {
            #pragma unroll
            for (int q = 0; q < 16; q++) if (q == wq) v[q] = -INFINITY;
            lv = v[0]; lq = 0;
            #pragma unroll
            for (int q = 1; q < 16; q++) if (v[q] > lv) { lv = v[q]; lq = q; }
        }
    }
}

// ---------------------------------------------------------------------------
// Per-batch GEMM (64x64 tile, 4x4/thread):
//   Z[b,o,n] = sum_c w[o,c]*x[b,c,n]   (+ Z2 with w[o,C+c] when DUAL)
template<bool DUAL>
__global__ __launch_bounds__(256)
void mm_kernel(const float* __restrict__ xin, const float* __restrict__ w,
               float* __restrict__ Z, float* __restrict__ Z2,
               int C, int O, int in_bstride, int wstride)
{
    __shared__ float xs[32][64];
    __shared__ float ws1[32][68];
    __shared__ float ws2[32][68];
    const int n0 = blockIdx.x * 64;
    const int o0 = blockIdx.y * 64;
    const int b  = blockIdx.z;
    const int tid = threadIdx.x;
    const int nl = (tid & 15) * 4;
    const int ol = (tid >> 4) * 4;
    float a1[4][4] = {{0.f}};
    float a2[4][4] = {{0.f}};
    const float* xb = xin + (size_t)b * in_bstride;

    for (int cc = 0; cc < C; cc += 32) {
        #pragma unroll
        for (int t = 0; t < 8; t++) {
            const int id = tid + t * 256;
            const int j = id >> 6, nn = id & 63;
            const int c = cc + j;
            xs[j][nn] = (c < C) ? xb[c * NPTS + n0 + nn] : 0.f;
        }
        #pragma unroll
        for (int t = 0; t < 8; t++) {
            const int id = tid + t * 256;
            const int j = id & 31, i = id >> 5;
            const int c = cc + j;
            ws1[j][i] = (c < C) ? w[(o0 + i) * wstride + c] : 0.f;
            if (DUAL) ws2[j][i] = (c < C) ? w[(o0 + i) * wstride + C + c] : 0.f;
        }
        __syncthreads();
        #pragma unroll
        for (int j = 0; j < 32; j++) {
            const float4 xv = *reinterpret_cast<const float4*>(&xs[j][nl]);
            const float4 wv = *reinterpret_cast<const float4*>(&ws1[j][ol]);
            const float xr[4] = {xv.x, xv.y, xv.z, xv.w};
            const float wr[4] = {wv.x, wv.y, wv.z, wv.w};
            #pragma unroll
            for (int oi = 0; oi < 4; oi++)
                #pragma unroll
                for (int ni = 0; ni < 4; ni++)
                    a1[oi][ni] = fmaf(wr[oi], xr[ni], a1[oi][ni]);
            if (DUAL) {
                const float4 w2 = *reinterpret_cast<const float4*>(&ws2[j][ol]);
                const float w2r[4] = {w2.x, w2.y, w2.z, w2.w};
                #pragma unroll
                for (int oi = 0; oi < 4; oi++)
                    #pragma unroll
                    for (int ni = 0; ni < 4; ni++)
                        a2[oi][ni] = fmaf(w2r[oi], xr[ni], a2[oi][ni]);
            }
        }
        __syncthreads();
    }

    #pragma unroll
    for (int oi = 0; oi < 4; oi++) {
        const int o = o0 + ol + oi;
        const float4 r1 = make_float4(a1[oi][0], a1[oi][1], a1[oi][2], a1[oi][3]);
        *reinterpret_cast<float4*>(Z + ((size_t)b * O + o) * NPTS + n0 + nl) = r1;
        if (DUAL) {
            const float4 r2 = make_float4(a2[oi][0], a2[oi][1], a2[oi][2], a2[oi][3]);
            *reinterpret_cast<float4*>(Z2 + ((size_t)b * O + o) * NPTS + n0 + nl) = r2;
        }
    }
}

// ---------------------------------------------------------------------------
// Layer-5 GEMM: C=O=512 fixed. 128n x 64o tile, 8x4/thread, fused affine+leaky.
// out[b,o,n] = leaky(s[o]*sum_c w[o,c]*x[b,c,n] + bias[o])
__global__ __launch_bounds__(256, 4)
void mm5_kernel(const float* __restrict__ xin, const float* __restrict__ w,
                const float* __restrict__ sv, const float* __restrict__ bvec,
                float* __restrict__ out)
{
    __shared__ float xs[32][128];    // 16 KB
    __shared__ float ws[32][68];     // 8.7 KB
    const int n0 = blockIdx.x * 128;
    const int o0 = blockIdx.y * 64;
    const int b  = blockIdx.z;
    const int tid = threadIdx.x;
    const int nl = (tid & 15) * 8;
    const int ol = (tid >> 4) * 4;
    float acc[4][8] = {{0.f}};
    const float* xb = xin + (size_t)b * (512 * NPTS);

    for (int cc = 0; cc < 512; cc += 32) {
        #pragma unroll
        for (int t = 0; t < 4; t++) {          // xs: 1024 float4s, 4/thread
            const int f = tid + t * 256;
            const int j = f >> 5, col = (f & 31) * 4;
            *reinterpret_cast<float4*>(&xs[j][col]) =
                *reinterpret_cast<const float4*>(&xb[(cc + j) * NPTS + n0 + col]);
        }
        #pragma unroll
        for (int t = 0; t < 2; t++) {          // ws: 64 o-rows x 32 c, transpose
            const int id = tid + t * 256;
            const int i = id & 63, jq = (id >> 6) * 4;
            const float4 wv = *reinterpret_cast<const float4*>(&w[(o0 + i) * 512 + cc + jq]);
            ws[jq + 0][i] = wv.x;
            ws[jq + 1][i] = wv.y;
            ws[jq + 2][i] = wv.z;
            ws[jq + 3][i] = wv.w;
        }
        __syncthreads();
        #pragma unroll
        for (int j = 0; j < 32; j++) {
            float xr[8], wr[4];
            *reinterpret_cast<float4*>(&xr[0]) = *reinterpret_cast<const float4*>(&xs[j][nl]);
            *reinterpret_cast<float4*>(&xr[4]) = *reinterpret_cast<const float4*>(&xs[j][nl + 4]);
            *reinterpret_cast<float4*>(&wr[0]) = *reinterpret_cast<const float4*>(&ws[j][ol]);
            #pragma unroll
            for (int oi = 0; oi < 4; oi++)
                #pragma unroll
                for (int ni = 0; ni < 8; ni++)
                    acc[oi][ni] = fmaf(wr[oi], xr[ni], acc[oi][ni]);
        }
        __syncthreads();
    }

    #pragma unroll
    for (int oi = 0; oi < 4; oi++) {
        const int o = o0 + ol + oi;
        const float s = sv[o], bb = bvec[o];
        float* zp = out + ((size_t)b * 512 + o) * NPTS + n0 + nl;
        #pragma unroll
        for (int h = 0; h < 2; h++) {
            float4 r;
            r.x = fmaf(s, acc[oi][h * 4 + 0], bb);
            r.y = fmaf(s, acc[oi][h * 4 + 1], bb);
            r.z = fmaf(s, acc[oi][h * 4 + 2], bb);
            r.w = fmaf(s, acc[oi][h * 4 + 3], bb);
            r.x = r.x >= 0.f ? r.x : 0.2f * r.x;
            r.y = r.y >= 0.f ? r.y : 0.2f * r.y;
            r.z = r.z >= 0.f ? r.z : 0.2f * r.z;
            r.w = r.w >= 0.f ? r.w : 0.2f * r.w;
            *reinterpret_cast<float4*>(zp + h * 4) = r;
        }
    }
}

// ---------------------------------------------------------------------------
// out[b, cho+o, n] = leaky(s[o]*(max_k Z[b,o,idx[b,n,k]] - Z[b,o,n] + Z2[b,o,n]) + bias[o])
__global__ __launch_bounds__(256)
void gather_kernel(const float* __restrict__ Z, const float* __restrict__ Z2,
                   const int* __restrict__ knn_idx,
                   const float* __restrict__ sv, const float* __restrict__ bvec,
                   float* __restrict__ outc, int O, int ch_off)
{
    __shared__ int idx_s[64][21];
    const int n0  = blockIdx.x * 64;
    const int og0 = blockIdx.y * 16;
    const int b   = blockIdx.z;
    const int tid = threadIdx.x;
    const int* ig = knn_idx + (size_t)(b * NPTS + n0) * KNN_K;
    for (int i = tid; i < 64 * KNN_K; i += 256) {
        const int nn = i / KNN_K, k = i - nn * KNN_K;
        idx_s[nn][k] = ig[i];
    }
    __syncthreads();
    const int nn = tid & 63;
    const int oo = tid >> 6;
    const int n  = n0 + nn;
    for (int oc = 0; oc < 16; oc += 4) {
        const int o = og0 + oc + oo;
        const float* zr = Z + ((size_t)b * O + o) * NPTS;
        float mx = -INFINITY;
        #pragma unroll
        for (int k = 0; k < KNN_K; k++)
            mx = fmaxf(mx, zr[idx_s[nn][k]]);
        const float cz = zr[n];
        const float z2 = Z2[((size_t)b * O + o) * NPTS + n];
        float y = fmaf(sv[o], (mx - cz + z2), bvec[o]);
        y = y >= 0.f ? y : 0.2f * y;
        outc[(size_t)b * (512 * NPTS) + (size_t)(ch_off + o) * NPTS + n] = y;
    }
}

// ---------------------------------------------------------------------------
// p_max/p_avg over n; x_equ[b, 0:512]=max, [512:1024]=mean
__global__ __launch_bounds__(256)
void reduce_kernel(const float* __restrict__ xinv, float* __restrict__ xequ)
{
    const int b = blockIdx.x >> 9;
    const int o = blockIdx.x & 511;
    const float* row = xinv + (size_t)blockIdx.x * NPTS;
    const int tid = threadIdx.x;
    const float4 val = *reinterpret_cast<const float4*>(&row[tid * 4]);
    float mx = fmaxf(fmaxf(val.x, val.y), fmaxf(val.z, val.w));
    float sm = (val.x + val.y) + (val.z + val.w);
    #pragma unroll
    for (int off = 32; off; off >>= 1) {
        mx = fmaxf(mx, __shfl_down(mx, off));
        sm += __shfl_down(sm, off);
    }
    __shared__ float smx[4], ssm[4];
    if ((tid & 63) == 0) { smx[tid >> 6] = mx; ssm[tid >> 6] = sm; }
    __syncthreads();
    if (tid == 0) {
        mx = fmaxf(fmaxf(smx[0], smx[1]), fmaxf(smx[2], smx[3]));
        sm = (ssm[0] + ssm[1]) + (ssm[2] + ssm[3]);
        xequ[b * 1024 + o] = mx;
        xequ[b * 1024 + 512 + o] = sm * (1.0f / 1024.0f);
    }
}

// ---------------------------------------------------------------------------
extern "C" void kernel_launch(void* const* d_in, const int* in_sizes, int n_in,
                              void* d_out, int out_size, void* d_ws, size_t ws_size,
                              hipStream_t stream)
{
    const float* x  = (const float*)d_in[0];
    const float* w1 = (const float*)d_in[1],  *s1 = (const float*)d_in[2],  *b1 = (const float*)d_in[3];
    const float* w2 = (const float*)d_in[4],  *s2 = (const float*)d_in[5],  *b2 = (const float*)d_in[6];
    const float* w3 = (const float*)d_in[7],  *s3 = (const float*)d_in[8],  *b3 = (const float*)d_in[9];
    const float* w4 = (const float*)d_in[10], *s4 = (const float*)d_in[11], *b4 = (const float*)d_in[12];
    const float* w5 = (const float*)d_in[13], *s5 = (const float*)d_in[14], *b5 = (const float*)d_in[15];

    float* out  = (float*)d_out;
    float* xequ = out;
    float* xinv = out + 16 * 1024;

    float* xc  = (float*)d_ws;                                // (16, 512, 1024)
    float* Z   = xc  + (size_t)16 * 512 * NPTS;               // (16, 256, 1024)
    float* Z2  = Z   + (size_t)16 * 256 * NPTS;               // (16, 256, 1024)
    int*   idxb = (int*)(Z2 + (size_t)16 * 256 * NPTS);       // (16, 1024, 20)

    const int BS_XC = 512 * NPTS;

    // ---- Layer 1: C=3, O=64, in=x ----
    knn_kernel<3><<<2048, 512, 0, stream>>>(x, idxb, 3 * NPTS);
    mm_kernel<true><<<dim3(16, 1, 16), 256, 0, stream>>>(
        x, w1, Z, Z2, 3, 64, 3 * NPTS, 6);
    gather_kernel<<<dim3(16, 4, 16), 256, 0, stream>>>(Z, Z2, idxb, s1, b1, xc, 64, 0);

    // ---- Layer 2: C=64, O=64, in=xc[:,0:64,:] ----
    knn_kernel<64><<<2048, 512, 0, stream>>>(xc, idxb, BS_XC);
    mm_kernel<true><<<dim3(16, 1, 16), 256, 0, stream>>>(
        xc, w2, Z, Z2, 64, 64, BS_XC, 128);
    gather_kernel<<<dim3(16, 4, 16), 256, 0, stream>>>(Z, Z2, idxb, s2, b2, xc, 64, 64);

    // ---- Layer 3: C=64, O=128, in=xc[:,64:128,:] ----
    {
        const float* in3 = xc + (size_t)64 * NPTS;
        knn_kernel<64><<<2048, 512, 0, stream>>>(in3, idxb, BS_XC);
        mm_kernel<true><<<dim3(16, 2, 16), 256, 0, stream>>>(
            in3, w3, Z, Z2, 64, 128, BS_XC, 128);
        gather_kernel<<<dim3(16, 8, 16), 256, 0, stream>>>(Z, Z2, idxb, s3, b3, xc, 128, 128);
    }

    // ---- Layer 4: C=128, O=256, in=xc[:,128:256,:] ----
    {
        const float* in4 = xc + (size_t)128 * NPTS;
        knn_kernel<128><<<2048, 512, 0, stream>>>(in4, idxb, BS_XC);
        mm_kernel<true><<<dim3(16, 4, 16), 256, 0, stream>>>(
            in4, w4, Z, Z2, 128, 256, BS_XC, 256);
        gather_kernel<<<dim3(16, 16, 16), 256, 0, stream>>>(Z, Z2, idxb, s4, b4, xc, 256, 256);
    }

    // ---- Layer 5: 512x512 pointwise conv + affine + leaky -> x_inv ----
    mm5_kernel<<<dim3(8, 8, 16), 256, 0, stream>>>(xc, w5, s5, b5, xinv);

    // ---- global max/mean pool -> x_equ ----
    reduce_kernel<<<8192, 256, 0, stream>>>(xinv, xequ);
}

// Round 9
// 850.969 us; speedup vs baseline: 1.1203x; 1.0441x over previous
//
#include <hip/hip_runtime.h>
#include <hip/hip_bf16.h>

#define NPTS 1024
#define KNN_K 20

// ---------------------------------------------------------------------------
// kNN: one block = 8 query rows of one batch, 256 threads (4 waves).
// Distance phase: each thread owns 4 columns for all 8 rows (acc[8][4]);
// xn rows preloaded into registers as float4 per 4-c chunk (ds_read_b128,
// 4x fewer LDS-read instructions than scalar broadcasts). No launch_bounds
// min-occupancy clamp: LDS caps the CU at 4 blocks x 4 waves, so VGPR up to
// 128 is free (r3's spill came from the (512,6) clamp, not the preload).
// Top-k: 32-lane group per row (two rows per wave, lane-parallel), values in
// registers. fmaf chain order over c matches the validated r2/r6 kernels.
template<int C>
__global__ __launch_bounds__(256)
void knn_kernel(const float* __restrict__ x, int* __restrict__ knn_idx,
                int in_bstride)
{
    __shared__ float dist[8][NPTS];      // 32 KB
    __shared__ float xn[8][C < 4 ? 4 : C];
    __shared__ float xxr[8];
    const int b  = blockIdx.x >> 7;            // 128 row-groups per batch
    const int n0 = (blockIdx.x & 127) << 3;
    const int tid = threadIdx.x;               // 0..255
    const float* xb = x + (size_t)b * in_bstride;

    for (int i = tid; i < 8 * C; i += 256) {
        const int r = i / C, c = i - r * C;
        xn[r][c] = xb[c * NPTS + n0 + r];
    }
    __syncthreads();
    if (tid < 8) {
        float s = 0.f;
        for (int c = 0; c < C; c++) s = fmaf(xn[tid][c], xn[tid][c], s);
        xxr[tid] = s;
    }
    __syncthreads();

    // --- distance phase: each thread owns m = 4*tid .. 4*tid+3 ---
    float acc[8][4];
    #pragma unroll
    for (int r = 0; r < 8; r++)
        acc[r][0] = acc[r][1] = acc[r][2] = acc[r][3] = 0.f;
    float sq[4] = {0.f, 0.f, 0.f, 0.f};        // xx[m] on the fly
    const int m0 = tid * 4;

    if constexpr (C % 4 == 0) {
        for (int c4 = 0; c4 < C; c4 += 4) {
            float4 xnv[8];
            #pragma unroll
            for (int r = 0; r < 8; r++)
                xnv[r] = *reinterpret_cast<const float4*>(&xn[r][c4]);
            #pragma unroll
            for (int u = 0; u < 4; u++) {
                const float4 xm = *reinterpret_cast<const float4*>(xb + (c4 + u) * NPTS + m0);
                sq[0] = fmaf(xm.x, xm.x, sq[0]);
                sq[1] = fmaf(xm.y, xm.y, sq[1]);
                sq[2] = fmaf(xm.z, xm.z, sq[2]);
                sq[3] = fmaf(xm.w, xm.w, sq[3]);
                #pragma unroll
                for (int r = 0; r < 8; r++) {
                    const float xv = (u == 0) ? xnv[r].x : (u == 1) ? xnv[r].y
                                   : (u == 2) ? xnv[r].z : xnv[r].w;
                    acc[r][0] = fmaf(xv, xm.x, acc[r][0]);
                    acc[r][1] = fmaf(xv, xm.y, acc[r][1]);
                    acc[r][2] = fmaf(xv, xm.z, acc[r][2]);
                    acc[r][3] = fmaf(xv, xm.w, acc[r][3]);
                }
            }
        }
    } else {
        for (int c = 0; c < C; c++) {
            const float4 xm = *reinterpret_cast<const float4*>(xb + c * NPTS + m0);
            sq[0] = fmaf(xm.x, xm.x, sq[0]);
            sq[1] = fmaf(xm.y, xm.y, sq[1]);
            sq[2] = fmaf(xm.z, xm.z, sq[2]);
            sq[3] = fmaf(xm.w, xm.w, sq[3]);
            #pragma unroll
            for (int r = 0; r < 8; r++) {
                const float xv = xn[r][c];
                acc[r][0] = fmaf(xv, xm.x, acc[r][0]);
                acc[r][1] = fmaf(xv, xm.y, acc[r][1]);
                acc[r][2] = fmaf(xv, xm.z, acc[r][2]);
                acc[r][3] = fmaf(xv, xm.w, acc[r][3]);
            }
        }
    }
    #pragma unroll
    for (int r = 0; r < 8; r++) {
        float4 dv;
        dv.x = 2.f * acc[r][0] - xxr[r] - sq[0];
        dv.y = 2.f * acc[r][1] - xxr[r] - sq[1];
        dv.z = 2.f * acc[r][2] - xxr[r] - sq[2];
        dv.w = 2.f * acc[r][3] - xxr[r] - sq[3];
        *reinterpret_cast<float4*>(&dist[r][m0]) = dv;
    }
    __syncthreads();

    // --- top-k phase: 32-lane group per row, values in registers ---
    const int r    = tid >> 5;
    const int lane = tid & 31;
    float v[32];
    #pragma unroll
    for (int q = 0; q < 32; q++) v[q] = dist[r][lane + 32 * q];

    float lv = v[0]; int lq = 0;
    #pragma unroll
    for (int q = 1; q < 32; q++) if (v[q] > lv) { lv = v[q]; lq = q; }

    int* outp = knn_idx + ((size_t)(b * NPTS + n0 + r)) * KNN_K;
    for (int k = 0; k < KNN_K; k++) {
        float bv_ = lv;
        int   bm  = lane + 32 * lq;
        #pragma unroll
        for (int off = 16; off; off >>= 1) {
            const float ov = __shfl_xor(bv_, off, 32);
            const int   om = __shfl_xor(bm, off, 32);
            if (ov > bv_ || (ov == bv_ && om < bm)) { bv_ = ov; bm = om; }
        }
        if (lane == 0) outp[k] = bm;
        const int wl = bm & 31, wq = bm >> 5;
        if (lane == wl) {
            #pragma unroll
            for (int q = 0; q < 32; q++) if (q == wq) v[q] = -INFINITY;
            lv = v[0]; lq = 0;
            #pragma unroll
            for (int q = 1; q < 32; q++) if (v[q] > lv) { lv = v[q]; lq = q; }
        }
    }
}

// ---------------------------------------------------------------------------
// Per-batch GEMM (64x64 tile, 4x4/thread):
//   Z[b,o,n] = sum_c w[o,c]*x[b,c,n]   (+ Z2 with w[o,C+c] when DUAL)
template<bool DUAL>
__global__ __launch_bounds__(256)
void mm_kernel(const float* __restrict__ xin, const float* __restrict__ w,
               float* __restrict__ Z, float* __restrict__ Z2,
               int C, int O, int in_bstride, int wstride)
{
    __shared__ float xs[32][64];
    __shared__ float ws1[32][68];
    __shared__ float ws2[32][68];
    const int n0 = blockIdx.x * 64;
    const int o0 = blockIdx.y * 64;
    const int b  = blockIdx.z;
    const int tid = threadIdx.x;
    const int nl = (tid & 15) * 4;
    const int ol = (tid >> 4) * 4;
    float a1[4][4] = {{0.f}};
    float a2[4][4] = {{0.f}};
    const float* xb = xin + (size_t)b * in_bstride;

    for (int cc = 0; cc < C; cc += 32) {
        #pragma unroll
        for (int t = 0; t < 8; t++) {
            const int id = tid + t * 256;
            const int j = id >> 6, nn = id & 63;
            const int c = cc + j;
            xs[j][nn] = (c < C) ? xb[c * NPTS + n0 + nn] : 0.f;
        }
        #pragma unroll
        for (int t = 0; t < 8; t++) {
            const int id = tid + t * 256;
            const int j = id & 31, i = id >> 5;
            const int c = cc + j;
            ws1[j][i] = (c < C) ? w[(o0 + i) * wstride + c] : 0.f;
            if (DUAL) ws2[j][i] = (c < C) ? w[(o0 + i) * wstride + C + c] : 0.f;
        }
        __syncthreads();
        #pragma unroll
        for (int j = 0; j < 32; j++) {
            const float4 xv = *reinterpret_cast<const float4*>(&xs[j][nl]);
            const float4 wv = *reinterpret_cast<const float4*>(&ws1[j][ol]);
            const float xr[4] = {xv.x, xv.y, xv.z, xv.w};
            const float wr[4] = {wv.x, wv.y, wv.z, wv.w};
            #pragma unroll
            for (int oi = 0; oi < 4; oi++)
                #pragma unroll
                for (int ni = 0; ni < 4; ni++)
                    a1[oi][ni] = fmaf(wr[oi], xr[ni], a1[oi][ni]);
            if (DUAL) {
                const float4 w2 = *reinterpret_cast<const float4*>(&ws2[j][ol]);
                const float w2r[4] = {w2.x, w2.y, w2.z, w2.w};
                #pragma unroll
                for (int oi = 0; oi < 4; oi++)
                    #pragma unroll
                    for (int ni = 0; ni < 4; ni++)
                        a2[oi][ni] = fmaf(w2r[oi], xr[ni], a2[oi][ni]);
            }
        }
        __syncthreads();
    }

    #pragma unroll
    for (int oi = 0; oi < 4; oi++) {
        const int o = o0 + ol + oi;
        const float4 r1 = make_float4(a1[oi][0], a1[oi][1], a1[oi][2], a1[oi][3]);
        *reinterpret_cast<float4*>(Z + ((size_t)b * O + o) * NPTS + n0 + nl) = r1;
        if (DUAL) {
            const float4 r2 = make_float4(a2[oi][0], a2[oi][1], a2[oi][2], a2[oi][3]);
            *reinterpret_cast<float4*>(Z2 + ((size_t)b * O + o) * NPTS + n0 + nl) = r2;
        }
    }
}

// ---------------------------------------------------------------------------
// Layer-5 GEMM: C=O=512 fixed. 128x128 tile, 8x8/thread, fused affine+leaky.
// out[b,o,n] = leaky(s[o]*sum_c w[o,c]*x[b,c,n] + bias[o])
__global__ __launch_bounds__(256)
void mm5_kernel(const float* __restrict__ xin, const float* __restrict__ w,
                const float* __restrict__ sv, const float* __restrict__ bvec,
                float* __restrict__ out)
{
    __shared__ float xs[32][128];    // 16 KB
    __shared__ float ws[32][128];    // 16 KB
    const int n0 = blockIdx.x * 128;
    const int o0 = blockIdx.y * 128;
    const int b  = blockIdx.z;
    const int tid = threadIdx.x;
    const int nl = (tid & 15) * 8;
    const int ol = (tid >> 4) * 8;
    float acc[8][8] = {{0.f}};
    const float* xb = xin + (size_t)b * (512 * NPTS);

    for (int cc = 0; cc < 512; cc += 32) {
        #pragma unroll
        for (int t = 0; t < 4; t++) {          // xs: 1024 float4s, 4/thread
            const int f = tid + t * 256;
            const int j = f >> 5, col = (f & 31) * 4;
            *reinterpret_cast<float4*>(&xs[j][col]) =
                *reinterpret_cast<const float4*>(&xb[(cc + j) * NPTS + n0 + col]);
        }
        #pragma unroll
        for (int t = 0; t < 4; t++) {          // ws: load f4 along c, transpose
            const int id = tid + t * 256;
            const int i = id & 127, jq = (id >> 7) * 4;
            const float4 wv = *reinterpret_cast<const float4*>(&w[(o0 + i) * 512 + cc + jq]);
            ws[jq + 0][i] = wv.x;
            ws[jq + 1][i] = wv.y;
            ws[jq + 2][i] = wv.z;
            ws[jq + 3][i] = wv.w;
        }
        __syncthreads();
        #pragma unroll
        for (int j = 0; j < 32; j++) {
            float xr[8], wr[8];
            *reinterpret_cast<float4*>(&xr[0]) = *reinterpret_cast<const float4*>(&xs[j][nl]);
            *reinterpret_cast<float4*>(&xr[4]) = *reinterpret_cast<const float4*>(&xs[j][nl + 4]);
            *reinterpret_cast<float4*>(&wr[0]) = *reinterpret_cast<const float4*>(&ws[j][ol]);
            *reinterpret_cast<float4*>(&wr[4]) = *reinterpret_cast<const float4*>(&ws[j][ol + 4]);
            #pragma unroll
            for (int oi = 0; oi < 8; oi++)
                #pragma unroll
                for (int ni = 0; ni < 8; ni++)
                    acc[oi][ni] = fmaf(wr[oi], xr[ni], acc[oi][ni]);
        }
        __syncthreads();
    }

    #pragma unroll
    for (int oi = 0; oi < 8; oi++) {
        const int o = o0 + ol + oi;
        const float s = sv[o], bb = bvec[o];
        float* zp = out + ((size_t)b * 512 + o) * NPTS + n0 + nl;
        #pragma unroll
        for (int h = 0; h < 2; h++) {
            float4 r;
            r.x = fmaf(s, acc[oi][h * 4 + 0], bb);
            r.y = fmaf(s, acc[oi][h * 4 + 1], bb);
            r.z = fmaf(s, acc[oi][h * 4 + 2], bb);
            r.w = fmaf(s, acc[oi][h * 4 + 3], bb);
            r.x = r.x >= 0.f ? r.x : 0.2f * r.x;
            r.y = r.y >= 0.f ? r.y : 0.2f * r.y;
            r.z = r.z >= 0.f ? r.z : 0.2f * r.z;
            r.w = r.w >= 0.f ? r.w : 0.2f * r.w;
            *reinterpret_cast<float4*>(zp + h * 4) = r;
        }
    }
}

// ---------------------------------------------------------------------------
// out[b, cho+o, n] = leaky(s[o]*(max_k Z[b,o,idx[b,n,k]] - Z[b,o,n] + Z2[b,o,n]) + bias[o])
__global__ __launch_bounds__(256)
void gather_kernel(const float* __restrict__ Z, const float* __restrict__ Z2,
                   const int* __restrict__ knn_idx,
                   const float* __restrict__ sv, const float* __restrict__ bvec,
                   float* __restrict__ outc, int O, int ch_off)
{
    __shared__ int idx_s[64][21];
    const int n0  = blockIdx.x * 64;
    const int og0 = blockIdx.y * 16;
    const int b   = blockIdx.z;
    const int tid = threadIdx.x;
    const int* ig = knn_idx + (size_t)(b * NPTS + n0) * KNN_K;
    for (int i = tid; i < 64 * KNN_K; i += 256) {
        const int nn = i / KNN_K, k = i - nn * KNN_K;
        idx_s[nn][k] = ig[i];
    }
    __syncthreads();
    const int nn = tid & 63;
    const int oo = tid >> 6;
    const int n  = n0 + nn;
    for (int oc = 0; oc < 16; oc += 4) {
        const int o = og0 + oc + oo;
        const float* zr = Z + ((size_t)b * O + o) * NPTS;
        float mx = -INFINITY;
        #pragma unroll
        for (int k = 0; k < KNN_K; k++)
            mx = fmaxf(mx, zr[idx_s[nn][k]]);
        const float cz = zr[n];
        const float z2 = Z2[((size_t)b * O + o) * NPTS + n];
        float y = fmaf(sv[o], (mx - cz + z2), bvec[o]);
        y = y >= 0.f ? y : 0.2f * y;
        outc[(size_t)b * (512 * NPTS) + (size_t)(ch_off + o) * NPTS + n] = y;
    }
}

// ---------------------------------------------------------------------------
// p_max/p_avg over n; x_equ[b, 0:512]=max, [512:1024]=mean
__global__ __launch_bounds__(256)
void reduce_kernel(const float* __restrict__ xinv, float* __restrict__ xequ)
{
    const int b = blockIdx.x >> 9;
    const int o = blockIdx.x & 511;
    const float* row = xinv + (size_t)blockIdx.x * NPTS;
    const int tid = threadIdx.x;
    const float4 val = *reinterpret_cast<const float4*>(&row[tid * 4]);
    float mx = fmaxf(fmaxf(val.x, val.y), fmaxf(val.z, val.w));
    float sm = (val.x + val.y) + (val.z + val.w);
    #pragma unroll
    for (int off = 32; off; off >>= 1) {
        mx = fmaxf(mx, __shfl_down(mx, off));
        sm += __shfl_down(sm, off);
    }
    __shared__ float smx[4], ssm[4];
    if ((tid & 63) == 0) { smx[tid >> 6] = mx; ssm[tid >> 6] = sm; }
    __syncthreads();
    if (tid == 0) {
        mx = fmaxf(fmaxf(smx[0], smx[1]), fmaxf(smx[2], smx[3]));
        sm = (ssm[0] + ssm[1]) + (ssm[2] + ssm[3]);
        xequ[b * 1024 + o] = mx;
        xequ[b * 1024 + 512 + o] = sm * (1.0f / 1024.0f);
    }
}

// ---------------------------------------------------------------------------
extern "C" void kernel_launch(void* const* d_in, const int* in_sizes, int n_in,
                              void* d_out, int out_size, void* d_ws, size_t ws_size,
                              hipStream_t stream)
{
    const float* x  = (const float*)d_in[0];
    const float* w1 = (const float*)d_in[1],  *s1 = (const float*)d_in[2],  *b1 = (const float*)d_in[3];
    const float* w2 = (const float*)d_in[4],  *s2 = (const float*)d_in[5],  *b2 = (const float*)d_in[6];
    const float* w3 = (const float*)d_in[7],  *s3 = (const float*)d_in[8],  *b3 = (const float*)d_in[9];
    const float* w4 = (const float*)d_in[10], *s4 = (const float*)d_in[11], *b4 = (const float*)d_in[12];
    const float* w5 = (const float*)d_in[13], *s5 = (const float*)d_in[14], *b5 = (const float*)d_in[15];

    float* out  = (float*)d_out;
    float* xequ = out;
    float* xinv = out + 16 * 1024;

    float* xc  = (float*)d_ws;                                // (16, 512, 1024)
    float* Z   = xc  + (size_t)16 * 512 * NPTS;               // (16, 256, 1024)
    float* Z2  = Z   + (size_t)16 * 256 * NPTS;               // (16, 256, 1024)
    int*   idxb = (int*)(Z2 + (size_t)16 * 256 * NPTS);       // (16, 1024, 20)

    const int BS_XC = 512 * NPTS;

    // ---- Layer 1: C=3, O=64, in=x ----
    knn_kernel<3><<<2048, 256, 0, stream>>>(x, idxb, 3 * NPTS);
    mm_kernel<true><<<dim3(16, 1, 16), 256, 0, stream>>>(
        x, w1, Z, Z2, 3, 64, 3 * NPTS, 6);
    gather_kernel<<<dim3(16, 4, 16), 256, 0, stream>>>(Z, Z2, idxb, s1, b1, xc, 64, 0);

    // ---- Layer 2: C=64, O=64, in=xc[:,0:64,:] ----
    knn_kernel<64><<<2048, 256, 0, stream>>>(xc, idxb, BS_XC);
    mm_kernel<true><<<dim3(16, 1, 16), 256, 0, stream>>>(
        xc, w2, Z, Z2, 64, 64, BS_XC, 128);
    gather_kernel<<<dim3(16, 4, 16), 256, 0, stream>>>(Z, Z2, idxb, s2, b2, xc, 64, 64);

    // ---- Layer 3: C=64, O=128, in=xc[:,64:128,:] ----
    {
        const float* in3 = xc + (size_t)64 * NPTS;
        knn_kernel<64><<<2048, 256, 0, stream>>>(in3, idxb, BS_XC);
        mm_kernel<true><<<dim3(16, 2, 16), 256, 0, stream>>>(
            in3, w3, Z, Z2, 64, 128, BS_XC, 128);
        gather_kernel<<<dim3(16, 8, 16), 256, 0, stream>>>(Z, Z2, idxb, s3, b3, xc, 128, 128);
    }

    // ---- Layer 4: C=128, O=256, in=xc[:,128:256,:] ----
    {
        const float* in4 = xc + (size_t)128 * NPTS;
        knn_kernel<128><<<2048, 256, 0, stream>>>(in4, idxb, BS_XC);
        mm_kernel<true><<<dim3(16, 4, 16), 256, 0, stream>>>(
            in4, w4, Z, Z2, 128, 256, BS_XC, 256);
        gather_kernel<<<dim3(16, 16, 16), 256, 0, stream>>>(Z, Z2, idxb, s4, b4, xc, 256, 256);
    }

    // ---- Layer 5: 512x512 pointwise conv + affine + leaky -> x_inv ----
    mm5_kernel<<<dim3(8, 4, 16), 256, 0, stream>>>(xc, w5, s5, b5, xinv);

    // ---- global max/mean pool -> x_equ ----
    reduce_kernel<<<8192, 256, 0, stream>>>(xinv, xequ);
}

// Round 14
// 755.340 us; speedup vs baseline: 1.2621x; 1.1266x over previous
//
#include <hip/hip_runtime.h>
#include <hip/hip_bf16.h>

#define NPTS 1024
#define KNN_K 20

// ---------------------------------------------------------------------------
// kNN: one block = 4 query rows of one batch, 256 threads (4 waves).
// ROWS=4 halves LDS (dist 16 KB) -> 8 blocks/CU, 32 waves/CU cap (was 29%
// occupancy at ROWS=8). Each thread owns 4 columns for all 4 rows; xn rows
// preloaded as float4 per 4-c chunk. Per-(r,m) fmaf chains over c are
// unchanged -> bit-identical distances -> identical indices.
// Top-k: one 64-lane wave per row, 16 values/lane (r6-validated structure).
template<int C>
__global__ __launch_bounds__(256)
void knn_kernel(const float* __restrict__ x, int* __restrict__ knn_idx,
                int in_bstride)
{
    __shared__ float dist[4][NPTS];      // 16 KB
    __shared__ float xn[4][C < 4 ? 4 : C];
    __shared__ float xxr[4];
    const int b  = blockIdx.x >> 8;            // 256 row-groups per batch
    const int n0 = (blockIdx.x & 255) << 2;
    const int tid = threadIdx.x;               // 0..255
    const float* xb = x + (size_t)b * in_bstride;

    for (int i = tid; i < 4 * C; i += 256) {
        const int r = i / C, c = i - r * C;
        xn[r][c] = xb[c * NPTS + n0 + r];
    }
    __syncthreads();
    if (tid < 4) {
        float s = 0.f;
        for (int c = 0; c < C; c++) s = fmaf(xn[tid][c], xn[tid][c], s);
        xxr[tid] = s;
    }
    __syncthreads();

    // --- distance phase: each thread owns m = 4*tid .. 4*tid+3 ---
    float acc[4][4];
    #pragma unroll
    for (int r = 0; r < 4; r++)
        acc[r][0] = acc[r][1] = acc[r][2] = acc[r][3] = 0.f;
    float sq[4] = {0.f, 0.f, 0.f, 0.f};        // xx[m] on the fly
    const int m0 = tid * 4;

    if constexpr (C % 4 == 0) {
        for (int c4 = 0; c4 < C; c4 += 4) {
            float4 xnv[4];
            #pragma unroll
            for (int r = 0; r < 4; r++)
                xnv[r] = *reinterpret_cast<const float4*>(&xn[r][c4]);
            #pragma unroll
            for (int u = 0; u < 4; u++) {
                const float4 xm = *reinterpret_cast<const float4*>(xb + (c4 + u) * NPTS + m0);
                sq[0] = fmaf(xm.x, xm.x, sq[0]);
                sq[1] = fmaf(xm.y, xm.y, sq[1]);
                sq[2] = fmaf(xm.z, xm.z, sq[2]);
                sq[3] = fmaf(xm.w, xm.w, sq[3]);
                #pragma unroll
                for (int r = 0; r < 4; r++) {
                    const float xv = (u == 0) ? xnv[r].x : (u == 1) ? xnv[r].y
                                   : (u == 2) ? xnv[r].z : xnv[r].w;
                    acc[r][0] = fmaf(xv, xm.x, acc[r][0]);
                    acc[r][1] = fmaf(xv, xm.y, acc[r][1]);
                    acc[r][2] = fmaf(xv, xm.z, acc[r][2]);
                    acc[r][3] = fmaf(xv, xm.w, acc[r][3]);
                }
            }
        }
    } else {
        for (int c = 0; c < C; c++) {
            const float4 xm = *reinterpret_cast<const float4*>(xb + c * NPTS + m0);
            sq[0] = fmaf(xm.x, xm.x, sq[0]);
            sq[1] = fmaf(xm.y, xm.y, sq[1]);
            sq[2] = fmaf(xm.z, xm.z, sq[2]);
            sq[3] = fmaf(xm.w, xm.w, sq[3]);
            #pragma unroll
            for (int r = 0; r < 4; r++) {
                const float xv = xn[r][c];
                acc[r][0] = fmaf(xv, xm.x, acc[r][0]);
                acc[r][1] = fmaf(xv, xm.y, acc[r][1]);
                acc[r][2] = fmaf(xv, xm.z, acc[r][2]);
                acc[r][3] = fmaf(xv, xm.w, acc[r][3]);
            }
        }
    }
    #pragma unroll
    for (int r = 0; r < 4; r++) {
        float4 dv;
        dv.x = 2.f * acc[r][0] - xxr[r] - sq[0];
        dv.y = 2.f * acc[r][1] - xxr[r] - sq[1];
        dv.z = 2.f * acc[r][2] - xxr[r] - sq[2];
        dv.w = 2.f * acc[r][3] - xxr[r] - sq[3];
        *reinterpret_cast<float4*>(&dist[r][m0]) = dv;
    }
    __syncthreads();

    // --- top-k phase: one 64-lane wave per row, 16 values per lane ---
    const int r    = tid >> 6;                 // 0..3
    const int lane = tid & 63;
    float v[16];
    #pragma unroll
    for (int q = 0; q < 16; q++) v[q] = dist[r][lane + 64 * q];

    float lv = v[0]; int lq = 0;
    #pragma unroll
    for (int q = 1; q < 16; q++) if (v[q] > lv) { lv = v[q]; lq = q; }

    int* outp = knn_idx + ((size_t)(b * NPTS + n0 + r)) * KNN_K;
    for (int k = 0; k < KNN_K; k++) {
        float bv_ = lv;
        int   bm  = lane + 64 * lq;
        #pragma unroll
        for (int off = 32; off; off >>= 1) {
            const float ov = __shfl_xor(bv_, off);
            const int   om = __shfl_xor(bm, off);
            if (ov > bv_ || (ov == bv_ && om < bm)) { bv_ = ov; bm = om; }
        }
        if (lane == 0) outp[k] = bm;
        const int wl = bm & 63, wq = bm >> 6;
        if (lane == wl) {
            #pragma unroll
            for (int q = 0; q < 16; q++) if (q == wq) v[q] = -INFINITY;
            lv = v[0]; lq = 0;
            #pragma unroll
            for (int q = 1; q < 16; q++) if (v[q] > lv) { lv = v[q]; lq = q; }
        }
    }
}

// ---------------------------------------------------------------------------
// Per-batch GEMM (64x64 tile, 4x4/thread):
//   Z[b,o,n] = sum_c w[o,c]*x[b,c,n]   (+ Z2 with w[o,C+c] when DUAL)
template<bool DUAL>
__global__ __launch_bounds__(256)
void mm_kernel(const float* __restrict__ xin, const float* __restrict__ w,
               float* __restrict__ Z, float* __restrict__ Z2,
               int C, int O, int in_bstride, int wstride)
{
    __shared__ float xs[32][64];
    __shared__ float ws1[32][68];
    __shared__ float ws2[32][68];
    const int n0 = blockIdx.x * 64;
    const int o0 = blockIdx.y * 64;
    const int b  = blockIdx.z;
    const int tid = threadIdx.x;
    const int nl = (tid & 15) * 4;
    const int ol = (tid >> 4) * 4;
    float a1[4][4] = {{0.f}};
    float a2[4][4] = {{0.f}};
    const float* xb = xin + (size_t)b * in_bstride;

    for (int cc = 0; cc < C; cc += 32) {
        #pragma unroll
        for (int t = 0; t < 8; t++) {
            const int id = tid + t * 256;
            const int j = id >> 6, nn = id & 63;
            const int c = cc + j;
            xs[j][nn] = (c < C) ? xb[c * NPTS + n0 + nn] : 0.f;
        }
        #pragma unroll
        for (int t = 0; t < 8; t++) {
            const int id = tid + t * 256;
            const int j = id & 31, i = id >> 5;
            const int c = cc + j;
            ws1[j][i] = (c < C) ? w[(o0 + i) * wstride + c] : 0.f;
            if (DUAL) ws2[j][i] = (c < C) ? w[(o0 + i) * wstride + C + c] : 0.f;
        }
        __syncthreads();
        #pragma unroll
        for (int j = 0; j < 32; j++) {
            const float4 xv = *reinterpret_cast<const float4*>(&xs[j][nl]);
            const float4 wv = *reinterpret_cast<const float4*>(&ws1[j][ol]);
            const float xr[4] = {xv.x, xv.y, xv.z, xv.w};
            const float wr[4] = {wv.x, wv.y, wv.z, wv.w};
            #pragma unroll
            for (int oi = 0; oi < 4; oi++)
                #pragma unroll
                for (int ni = 0; ni < 4; ni++)
                    a1[oi][ni] = fmaf(wr[oi], xr[ni], a1[oi][ni]);
            if (DUAL) {
                const float4 w2 = *reinterpret_cast<const float4*>(&ws2[j][ol]);
                const float w2r[4] = {w2.x, w2.y, w2.z, w2.w};
                #pragma unroll
                for (int oi = 0; oi < 4; oi++)
                    #pragma unroll
                    for (int ni = 0; ni < 4; ni++)
                        a2[oi][ni] = fmaf(w2r[oi], xr[ni], a2[oi][ni]);
            }
        }
        __syncthreads();
    }

    #pragma unroll
    for (int oi = 0; oi < 4; oi++) {
        const int o = o0 + ol + oi;
        const float4 r1 = make_float4(a1[oi][0], a1[oi][1], a1[oi][2], a1[oi][3]);
        *reinterpret_cast<float4*>(Z + ((size_t)b * O + o) * NPTS + n0 + nl) = r1;
        if (DUAL) {
            const float4 r2 = make_float4(a2[oi][0], a2[oi][1], a2[oi][2], a2[oi][3]);
            *reinterpret_cast<float4*>(Z2 + ((size_t)b * O + o) * NPTS + n0 + nl) = r2;
        }
    }
}

// ---------------------------------------------------------------------------
// Layer-5 GEMM: C=O=512 fixed. 128x128 tile, 8x8/thread, fused affine+leaky.
// out[b,o,n] = leaky(s[o]*sum_c w[o,c]*x[b,c,n] + bias[o])
__global__ __launch_bounds__(256)
void mm5_kernel(const float* __restrict__ xin, const float* __restrict__ w,
                const float* __restrict__ sv, const float* __restrict__ bvec,
                float* __restrict__ out)
{
    __shared__ float xs[32][128];    // 16 KB
    __shared__ float ws[32][128];    // 16 KB
    const int n0 = blockIdx.x * 128;
    const int o0 = blockIdx.y * 128;
    const int b  = blockIdx.z;
    const int tid = threadIdx.x;
    const int nl = (tid & 15) * 8;
    const int ol = (tid >> 4) * 8;
    float acc[8][8] = {{0.f}};
    const float* xb = xin + (size_t)b * (512 * NPTS);

    for (int cc = 0; cc < 512; cc += 32) {
        #pragma unroll
        for (int t = 0; t < 4; t++) {          // xs: 1024 float4s, 4/thread
            const int f = tid + t * 256;
            const int j = f >> 5, col = (f & 31) * 4;
            *reinterpret_cast<float4*>(&xs[j][col]) =
                *reinterpret_cast<const float4*>(&xb[(cc + j) * NPTS + n0 + col]);
        }
        #pragma unroll
        for (int t = 0; t < 4; t++) {          // ws: load f4 along c, transpose
            const int id = tid + t * 256;
            const int i = id & 127, jq = (id >> 7) * 4;
            const float4 wv = *reinterpret_cast<const float4*>(&w[(o0 + i) * 512 + cc + jq]);
            ws[jq + 0][i] = wv.x;
            ws[jq + 1][i] = wv.y;
            ws[jq + 2][i] = wv.z;
            ws[jq + 3][i] = wv.w;
        }
        __syncthreads();
        #pragma unroll
        for (int j = 0; j < 32; j++) {
            float xr[8], wr[8];
            *reinterpret_cast<float4*>(&xr[0]) = *reinterpret_cast<const float4*>(&xs[j][nl]);
            *reinterpret_cast<float4*>(&xr[4]) = *reinterpret_cast<const float4*>(&xs[j][nl + 4]);
            *reinterpret_cast<float4*>(&wr[0]) = *reinterpret_cast<const float4*>(&ws[j][ol]);
            *reinterpret_cast<float4*>(&wr[4]) = *reinterpret_cast<const float4*>(&ws[j][ol + 4]);
            #pragma unroll
            for (int oi = 0; oi < 8; oi++)
                #pragma unroll
                for (int ni = 0; ni < 8; ni++)
                    acc[oi][ni] = fmaf(wr[oi], xr[ni], acc[oi][ni]);
        }
        __syncthreads();
    }

    #pragma unroll
    for (int oi = 0; oi < 8; oi++) {
        const int o = o0 + ol + oi;
        const float s = sv[o], bb = bvec[o];
        float* zp = out + ((size_t)b * 512 + o) * NPTS + n0 + nl;
        #pragma unroll
        for (int h = 0; h < 2; h++) {
            float4 r;
            r.x = fmaf(s, acc[oi][h * 4 + 0], bb);
            r.y = fmaf(s, acc[oi][h * 4 + 1], bb);
            r.z = fmaf(s, acc[oi][h * 4 + 2], bb);
            r.w = fmaf(s, acc[oi][h * 4 + 3], bb);
            r.x = r.x >= 0.f ? r.x : 0.2f * r.x;
            r.y = r.y >= 0.f ? r.y : 0.2f * r.y;
            r.z = r.z >= 0.f ? r.z : 0.2f * r.z;
            r.w = r.w >= 0.f ? r.w : 0.2f * r.w;
            *reinterpret_cast<float4*>(zp + h * 4) = r;
        }
    }
}

// ---------------------------------------------------------------------------
// Gather (LDS-staged): stage a 16-row o-tile of Z in LDS (64 KB, coalesced),
// then the 20-way neighbor-max becomes ds_read_b32 gathers (random banks ~
// 2-4-way conflict) instead of line-serialized vmem scatters through L1/L2.
// out[b, cho+o, n] = leaky(s[o]*(max_k Z[b,o,idx[b,n,k]] - Z[b,o,n] + Z2[b,o,n]) + bias[o])
__global__ __launch_bounds__(256)
void gather_kernel(const float* __restrict__ Z, const float* __restrict__ Z2,
                   const int* __restrict__ knn_idx,
                   const float* __restrict__ sv, const float* __restrict__ bvec,
                   float* __restrict__ outc, int O, int ch_off, int nper)
{
    __shared__ float zs[16][NPTS];   // 64 KB
    const int ot  = blockIdx.x * 16;
    const int n00 = blockIdx.y * nper;
    const int b   = blockIdx.z;
    const int tid = threadIdx.x;
    const float* Zb = Z + ((size_t)b * O + ot) * NPTS;

    #pragma unroll
    for (int t = 0; t < 16; t++) {           // 4096 float4s, 16/thread
        const int f = tid + t * 256;
        const int row = f >> 8, col = (f & 255) * 4;
        *reinterpret_cast<float4*>(&zs[row][col]) =
            *reinterpret_cast<const float4*>(&Zb[row * NPTS + col]);
    }
    __syncthreads();

    for (int nc = 0; nc < nper; nc += 256) {
        const int n = n00 + nc + tid;
        const int* ip = knn_idx + ((size_t)(b * NPTS + n)) * KNN_K;
        int idx[KNN_K];
        #pragma unroll
        for (int k = 0; k < KNN_K; k++) idx[k] = ip[k];
        #pragma unroll 4
        for (int oi = 0; oi < 16; oi++) {
            float mx = -INFINITY;
            #pragma unroll
            for (int k = 0; k < KNN_K; k++)
                mx = fmaxf(mx, zs[oi][idx[k]]);
            const int o = ot + oi;
            const float cz = zs[oi][n];
            const float z2 = Z2[((size_t)b * O + o) * NPTS + n];
            float y = fmaf(sv[o], (mx - cz + z2), bvec[o]);
            y = y >= 0.f ? y : 0.2f * y;
            outc[(size_t)b * (512 * NPTS) + (size_t)(ch_off + o) * NPTS + n] = y;
        }
    }
}

// ---------------------------------------------------------------------------
// p_max/p_avg over n; x_equ[b, 0:512]=max, [512:1024]=mean
__global__ __launch_bounds__(256)
void reduce_kernel(const float* __restrict__ xinv, float* __restrict__ xequ)
{
    const int b = blockIdx.x >> 9;
    const int o = blockIdx.x & 511;
    const float* row = xinv + (size_t)blockIdx.x * NPTS;
    const int tid = threadIdx.x;
    const float4 val = *reinterpret_cast<const float4*>(&row[tid * 4]);
    float mx = fmaxf(fmaxf(val.x, val.y), fmaxf(val.z, val.w));
    float sm = (val.x + val.y) + (val.z + val.w);
    #pragma unroll
    for (int off = 32; off; off >>= 1) {
        mx = fmaxf(mx, __shfl_down(mx, off));
        sm += __shfl_down(sm, off);
    }
    __shared__ float smx[4], ssm[4];
    if ((tid & 63) == 0) { smx[tid >> 6] = mx; ssm[tid >> 6] = sm; }
    __syncthreads();
    if (tid == 0) {
        mx = fmaxf(fmaxf(smx[0], smx[1]), fmaxf(smx[2], smx[3]));
        sm = (ssm[0] + ssm[1]) + (ssm[2] + ssm[3]);
        xequ[b * 1024 + o] = mx;
        xequ[b * 1024 + 512 + o] = sm * (1.0f / 1024.0f);
    }
}

// ---------------------------------------------------------------------------
extern "C" void kernel_launch(void* const* d_in, const int* in_sizes, int n_in,
                              void* d_out, int out_size, void* d_ws, size_t ws_size,
                              hipStream_t stream)
{
    const float* x  = (const float*)d_in[0];
    const float* w1 = (const float*)d_in[1],  *s1 = (const float*)d_in[2],  *b1 = (const float*)d_in[3];
    const float* w2 = (const float*)d_in[4],  *s2 = (const float*)d_in[5],  *b2 = (const float*)d_in[6];
    const float* w3 = (const float*)d_in[7],  *s3 = (const float*)d_in[8],  *b3 = (const float*)d_in[9];
    const float* w4 = (const float*)d_in[10], *s4 = (const float*)d_in[11], *b4 = (const float*)d_in[12];
    const float* w5 = (const float*)d_in[13], *s5 = (const float*)d_in[14], *b5 = (const float*)d_in[15];

    float* out  = (float*)d_out;
    float* xequ = out;
    float* xinv = out + 16 * 1024;

    float* xc  = (float*)d_ws;                                // (16, 512, 1024)
    float* Z   = xc  + (size_t)16 * 512 * NPTS;               // (16, 256, 1024)
    float* Z2  = Z   + (size_t)16 * 256 * NPTS;               // (16, 256, 1024)
    int*   idxb = (int*)(Z2 + (size_t)16 * 256 * NPTS);       // (16, 1024, 20)

    const int BS_XC = 512 * NPTS;

    // ---- Layer 1: C=3, O=64, in=x ----
    knn_kernel<3><<<4096, 256, 0, stream>>>(x, idxb, 3 * NPTS);
    mm_kernel<true><<<dim3(16, 1, 16), 256, 0, stream>>>(
        x, w1, Z, Z2, 3, 64, 3 * NPTS, 6);
    gather_kernel<<<dim3(4, 4, 16), 256, 0, stream>>>(Z, Z2, idxb, s1, b1, xc, 64, 0, 256);

    // ---- Layer 2: C=64, O=64, in=xc[:,0:64,:] ----
    knn_kernel<64><<<4096, 256, 0, stream>>>(xc, idxb, BS_XC);
    mm_kernel<true><<<dim3(16, 1, 16), 256, 0, stream>>>(
        xc, w2, Z, Z2, 64, 64, BS_XC, 128);
    gather_kernel<<<dim3(4, 4, 16), 256, 0, stream>>>(Z, Z2, idxb, s2, b2, xc, 64, 64, 256);

    // ---- Layer 3: C=64, O=128, in=xc[:,64:128,:] ----
    {
        const float* in3 = xc + (size_t)64 * NPTS;
        knn_kernel<64><<<4096, 256, 0, stream>>>(in3, idxb, BS_XC);
        mm_kernel<true><<<dim3(16, 2, 16), 256, 0, stream>>>(
            in3, w3, Z, Z2, 64, 128, BS_XC, 128);
        gather_kernel<<<dim3(8, 2, 16), 256, 0, stream>>>(Z, Z2, idxb, s3, b3, xc, 128, 128, 512);
    }

    // ---- Layer 4: C=128, O=256, in=xc[:,128:256,:] ----
    {
        const float* in4 = xc + (size_t)128 * NPTS;
        knn_kernel<128><<<4096, 256, 0, stream>>>(in4, idxb, BS_XC);
        mm_kernel<true><<<dim3(16, 4, 16), 256, 0, stream>>>(
            in4, w4, Z, Z2, 128, 256, BS_XC, 256);
        gather_kernel<<<dim3(16, 1, 16), 256, 0, stream>>>(Z, Z2, idxb, s4, b4, xc, 256, 256, 1024);
    }

    // ---- Layer 5: 512x512 pointwise conv + affine + leaky -> x_inv ----
    mm5_kernel<<<dim3(8, 4, 16), 256, 0, stream>>>(xc, w5, s5, b5, xinv);

    // ---- global max/mean pool -> x_equ ----
    reduce_kernel<<<8192, 256, 0, stream>>>(xinv, xequ);
}